// Round 2
// baseline (942.684 us; speedup 1.0000x reference)
//
#include <hip/hip_runtime.h>
#include <math.h>

// Problem constants
#define BROWS 32768
#define DDIM  4096
#define NEXP  64
#define NSTEP 128          // K-steps of 32
#define LSTR  132          // epilogue LDS row stride (floats)

typedef __attribute__((ext_vector_type(8))) short  short8;
typedef __attribute__((ext_vector_type(4))) float  float4v;

static __device__ __forceinline__ unsigned int f2bf_u(float f) {
    union { float f; unsigned int u; } v; v.f = f;
    unsigned int r = v.u + 0x7FFFu + ((v.u >> 16) & 1u);   // RNE
    return r >> 16;
}

// pack two fp32 -> packed bf16 (RTZ) with one v_perm_b32
static __device__ __forceinline__ unsigned int pk_perm(float lo, float hi) {
    union { float f; unsigned int u; } a, b; a.f = lo; b.f = hi;
    // dst = {hi.b3, hi.b2, lo.b3, lo.b2} -> sel bytes {2,3} from src1(lo), {6,7} from src0(hi)
    return __builtin_amdgcn_perm(b.u, a.u, 0x07060302u);
}

// ---------------------------------------------------------------------------
// Pre-pass: Bt[n][k] = bf16( n<64 ? gate_w[k][n] : w_noise[k][n-64] ), k-major
// ---------------------------------------------------------------------------
__global__ void bt_prepass(const float* __restrict__ gw, const float* __restrict__ wn,
                           unsigned short* __restrict__ Bt) {
    int tid = blockIdx.x * 256 + threadIdx.x;    // 128*4096 total
    int k = tid & (DDIM - 1);
    int n = tid >> 12;
    float v = (n < NEXP) ? gw[(size_t)k * NEXP + n] : wn[(size_t)k * NEXP + (n - NEXP)];
    Bt[(size_t)n * DDIM + k] = (unsigned short)f2bf_u(v);
}

// ---------------------------------------------------------------------------
// Main kernel: one wave per block, 16 rows per wave, all 128 cols per wave.
// No LDS staging, no barriers in the K-loop — loads stream from global.
// ---------------------------------------------------------------------------
__global__ __launch_bounds__(64) void moe_router(
    const float* __restrict__ x, const float* __restrict__ gate_b,
    const float* __restrict__ noise, const unsigned short* __restrict__ Bt,
    float* __restrict__ out_gates, float* __restrict__ out_idx,
    float* __restrict__ g_imp, float* __restrict__ g_load)
{
    __shared__ float Lw[16][LSTR];   // [row][0:64)=clean, [64:128)=noise logits

    const int ln  = threadIdx.x;     // 0..63
    const int q   = ln >> 4;
    const int l15 = ln & 15;
    const int row0 = blockIdx.x * 16;

    // A: lane l15 = row, quad q covers k = q*8 .. q*8+7 within each 32-k step
    const float4* ap = (const float4*)(x + (size_t)(row0 + l15) * DDIM + q * 8);
    // B: lane l15 = col-within-tile; tile nt offset = nt*16 rows of 4096 shorts
    const uint4*  bp = (const uint4*)(Bt + (size_t)l15 * DDIM + q * 8);

    float4v acc[8];
#pragma unroll
    for (int nt = 0; nt < 8; ++nt) acc[nt] = (float4v)0.f;

    float4 a0, a1, na0, na1;
    uint4  b[8], nb[8];

    // prologue: load step 0
    a0 = ap[0]; a1 = ap[1];
#pragma unroll
    for (int nt = 0; nt < 8; ++nt) b[nt] = bp[(size_t)nt * 8192];

    for (int s = 0; s < NSTEP - 1; ++s) {
        // prefetch step s+1 (independent of current compute)
        na0 = ap[(s + 1) * 8];
        na1 = ap[(s + 1) * 8 + 1];
#pragma unroll
        for (int nt = 0; nt < 8; ++nt) nb[nt] = bp[(size_t)nt * 8192 + (s + 1) * 4];

        // compute step s
        union { uint4 u; short8 s8; } pa;
        pa.u.x = pk_perm(a0.x, a0.y);
        pa.u.y = pk_perm(a0.z, a0.w);
        pa.u.z = pk_perm(a1.x, a1.y);
        pa.u.w = pk_perm(a1.z, a1.w);
#pragma unroll
        for (int nt = 0; nt < 8; ++nt) {
            union { uint4 u; short8 s8; } pb; pb.u = b[nt];
            acc[nt] = __builtin_amdgcn_mfma_f32_16x16x32_bf16(pa.s8, pb.s8, acc[nt], 0, 0, 0);
        }
        // rotate
        a0 = na0; a1 = na1;
#pragma unroll
        for (int nt = 0; nt < 8; ++nt) b[nt] = nb[nt];
    }
    // final step
    {
        union { uint4 u; short8 s8; } pa;
        pa.u.x = pk_perm(a0.x, a0.y);
        pa.u.y = pk_perm(a0.z, a0.w);
        pa.u.z = pk_perm(a1.x, a1.y);
        pa.u.w = pk_perm(a1.z, a1.w);
#pragma unroll
        for (int nt = 0; nt < 8; ++nt) {
            union { uint4 u; short8 s8; } pb; pb.u = b[nt];
            acc[nt] = __builtin_amdgcn_mfma_f32_16x16x32_bf16(pa.s8, pb.s8, acc[nt], 0, 0, 0);
        }
    }

    // ---- epilogue: dump logits to LDS (C-layout: row = q*4+r, col = nt*16+l15)
#pragma unroll
    for (int nt = 0; nt < 8; ++nt)
#pragma unroll
        for (int r = 0; r < 4; ++r)
            Lw[q * 4 + r][nt * 16 + l15] = acc[nt][r];
    __syncthreads();   // single wave: just orders LDS write->read

    const int e = ln;
    const float gbv = gate_b[e];
    float imp_acc = 0.f, load_acc = 0.f;

    for (int m = 0; m < 16; ++m) {
        float cl = Lw[m][e] + gbv;
        float nz = Lw[m][64 + e];
        float nv = noise[(size_t)(row0 + m) * NEXP + e];
        float sp = (nz > 0.f) ? (nz + log1pf(expf(-nz))) : log1pf(expf(nz));
        float lg = cl + nv * sp;

        // top-2 butterfly over 64 lanes, ties -> lower index
        float v1 = lg, v2 = -INFINITY;
        int   i1 = e,  i2 = 127;
#pragma unroll
        for (int msk = 1; msk < 64; msk <<= 1) {
            float o1 = __shfl_xor(v1, msk, 64);
            int  oi1 = __shfl_xor(i1, msk, 64);
            float o2 = __shfl_xor(v2, msk, 64);
            int  oi2 = __shfl_xor(i2, msk, 64);
            bool ofirst = (o1 > v1) || (o1 == v1 && oi1 < i1);
            if (ofirst) {
                bool t2 = (v1 > o2) || (v1 == o2 && i1 < oi2);
                v2 = t2 ? v1 : o2;  i2 = t2 ? i1 : oi2;
                v1 = o1;            i1 = oi1;
            } else {
                bool t2 = (o1 > v2) || (o1 == v2 && oi1 < i2);
                v2 = t2 ? o1 : v2;  i2 = t2 ? oi1 : i2;
            }
        }
        // softmax prob for importance (v1 is the row max)
        float p = expf(lg - v1);
        float ssum = p;
#pragma unroll
        for (int msk = 1; msk < 64; msk <<= 1) ssum += __shfl_xor(ssum, msk, 64);
        imp_acc += p / ssum;
        load_acc += (e == i1 ? 1.f : 0.f) + (e == i2 ? 1.f : 0.f);

        if (ln == 0) {
            float g1 = 1.f / (1.f + expf(v2 - v1));
            size_t rr = (size_t)(row0 + m) * 2;
            out_gates[rr]     = g1;
            out_gates[rr + 1] = 1.f - g1;
            out_idx[rr]     = (float)i1;
            out_idx[rr + 1] = (float)i2;
        }
    }
    atomicAdd(&g_imp[e], imp_acc);
    atomicAdd(&g_load[e], load_acc);
}

// ---------------------------------------------------------------------------
// aux_loss = mean(importance * load) * E^2 = 64 * sum(imp*load)
// ---------------------------------------------------------------------------
__global__ void aux_k(const float* __restrict__ imp, const float* __restrict__ ld,
                      float* __restrict__ out) {
    int e = threadIdx.x;
    float s = imp[e] * ld[e];
#pragma unroll
    for (int msk = 1; msk < 64; msk <<= 1) s += __shfl_xor(s, msk, 64);
    if (e == 0) out[0] = s * 64.f;
}

extern "C" void kernel_launch(void* const* d_in, const int* in_sizes, int n_in,
                              void* d_out, int out_size, void* d_ws, size_t ws_size,
                              hipStream_t stream) {
    const float* x     = (const float*)d_in[0];
    const float* gw    = (const float*)d_in[1];
    const float* gb    = (const float*)d_in[2];
    const float* wn    = (const float*)d_in[3];
    const float* noise = (const float*)d_in[4];
    float* out = (float*)d_out;

    float* g_imp  = (float*)d_ws;                               // [64]
    float* g_load = g_imp + 64;                                 // [64]
    unsigned short* Bt = (unsigned short*)((char*)d_ws + 1024); // [128][4096] bf16 = 1MB

    hipMemsetAsync(d_ws, 0, 512, stream);                       // zero g_imp/g_load
    bt_prepass<<<dim3((128 * DDIM) / 256), dim3(256), 0, stream>>>(gw, wn, Bt);
    moe_router<<<dim3(BROWS / 16), dim3(64), 0, stream>>>(
        x, gb, noise, Bt, out, out + (size_t)BROWS * 2, g_imp, g_load);
    aux_k<<<dim3(1), dim3(64), 0, stream>>>(g_imp, g_load, out + (size_t)BROWS * 4);
}